// Round 6
// baseline (234.883 us; speedup 1.0000x reference)
//
#include <hip/hip_runtime.h>
#include <hip/hip_bf16.h>
#include <stdint.h>

#define T_SEQ 2048
#define DH    128
#define BKV   64
#define QSCALE 0.12751742796f   // (1/sqrt(128)) * log2(e): exp2-domain softmax
#define SLOT_F 16640             // partial slot: m[128], s[128], O[128][128] floats
#define WS_NEEDED 55115776ULL    // 16.8MB bf16 K/V^T + 38.3MB partials (576 slots)

typedef short  short8 __attribute__((ext_vector_type(8)));
typedef __bf16 bf16x8 __attribute__((ext_vector_type(8)));
typedef float  f32x4  __attribute__((ext_vector_type(4)));

__device__ __forceinline__ bf16x8 as_bf16x8(short8 x) { return __builtin_bit_cast(bf16x8, x); }

__device__ __forceinline__ uint32_t bf_bits(float x) {
  union { __hip_bfloat16 h; unsigned short u; } cv;
  cv.h = __float2bfloat16(x);
  return (uint32_t)cv.u;
}

// ---------------- merged pre-pass: K fp32->bf16, V[n][t][d] -> Vt[n][d][t] bf16 ----------------
// grid (320, 16), 256 threads. x<256: K convert (65536 float4 per n). x>=256: V 64x64 transpose tile.
__global__ void prep_kv(const float* __restrict__ k, const float* __restrict__ v,
                        unsigned short* __restrict__ kb, unsigned short* __restrict__ vt) {
  __shared__ float tile[64][65];
  const int n = blockIdx.y, x = blockIdx.x, tid = threadIdx.x;
  if (x < 256) {
    const int i = (n * 256 + x) * 256 + tid;     // float4 index into K
    const float4 f = ((const float4*)k)[i];
    union { unsigned short us[4]; uint2 u2; } o;
    o.us[0] = (unsigned short)bf_bits(f.x);
    o.us[1] = (unsigned short)bf_bits(f.y);
    o.us[2] = (unsigned short)bf_bits(f.z);
    o.us[3] = (unsigned short)bf_bits(f.w);
    ((uint2*)kb)[i] = o.u2;
  } else {
    const int x2 = x - 256;
    const int t0 = (x2 & 31) * 64, d0 = (x2 >> 5) * 64;
    const int tx = tid & 63, ty = tid >> 6;      // (64, 4)
    #pragma unroll
    for (int i = 0; i < 64; i += 4)
      tile[ty + i][tx] = v[((size_t)n * T_SEQ + t0 + ty + i) * DH + d0 + tx];
    __syncthreads();
    #pragma unroll
    for (int i = 0; i < 64; i += 4)
      vt[((size_t)n * DH + d0 + ty + i) * T_SEQ + t0 + tx] = (unsigned short)bf_bits(tile[tx][ty + i]);
  }
}

// ---------------- flash attention fwd (causal), bf16 MFMA, 8-wave blocks, uniform KV-chunks ----------------
// Block = one job (n, Q, chunk c): 128 q-rows (wave w owns rows Q*128+16w..+15), KV tiles
// kt in [8c, min(8c+8, 2Q+2)). 8 waves share one 32KB K/V LDS tile -> wave-level overlap of
// softmax chains with MFMAs. Single-chunk q-blocks write Out directly; split blocks write
// unnormalized (m, s, O) partials, merged by combine_kernel. use_split=0 falls back to one
// job per q-block.
// S^T = mfma(A=K_tile, B=Q): lane holds S for q = lane&15, kv = 16*ma + 4*(lane>>4) + reg.
// O^T = mfma(A=V^T_tile, B=P^T): lane holds O for q = lane&15, d = 16*dsub + 4*(lane>>4) + reg.
// Fragment layout (HW-verified, m97/m89): A/B lane l <-> [l&15][(l>>4)*8+j]; C/D col=l&15, row=(l>>4)*4+reg.
__global__ __launch_bounds__(512, 6) void attn_fwd(
    const float* __restrict__ Qf,
    const unsigned short* __restrict__ Kb,
    const unsigned short* __restrict__ Vt,
    float* __restrict__ Out,
    float* __restrict__ Part,
    const int* __restrict__ maskp,
    int use_split)
{
  __shared__ __align__(16) char smem[32768];  // K tile @0 (16KB), V^T tile @16384 (16KB)

  const int tid  = threadIdx.x;
  const int lane = tid & 63;
  const int w    = tid >> 6;                  // 0..7
  const int m15  = lane & 15;
  const int g    = lane >> 4;

  // XCD L2 affinity: XCD = bid%8 serves n in {r, r+8} (2MB K+V bf16 < 4MB per-XCD L2).
  const int bid = blockIdx.x;
  const int n   = (bid & 7) + 8 * ((bid >> 3) & 1);
  const int job = bid >> 4;                    // 0..39
  const int masked = maskp[0];

  int Q, c, k0, k1, nc;
  if (masked && use_split) {
    // jobs enumerate (Q, chunk): tiles(Q) = 2Q+2, nc(Q) = ceil((2Q+2)/8) = (2Q+9)>>3; sum = 40.
    int base = 0; Q = 0;
    for (;;) { int ncq = (2 * Q + 9) >> 3; if (job < base + ncq) { c = job - base; break; } base += ncq; ++Q; }
    nc = (2 * Q + 9) >> 3;
    k0 = c * 8;
    k1 = min(k0 + 8, 2 * Q + 2);
  } else {
    if (job >= 16) return;                     // fallback / unmasked: one job per q-block
    Q = job; c = 0; nc = 1; k0 = 0;
    k1 = masked ? (2 * Q + 2) : (T_SEQ / BKV);
  }

  const int qrow = Q * 128 + 16 * w + m15;

  // Q B-fragments, fp32 -> bf16 in-kernel with scale*log2e folded:
  // lane needs Q[q-row][k = 32*kf + 8*g + j], j=0..7.
  bf16x8 qf[4];
  {
    const float* qg = Qf + ((size_t)n * T_SEQ + qrow) * DH;
    #pragma unroll
    for (int kf = 0; kf < 4; ++kf) {
      const float4 f0 = *(const float4*)(qg + 32 * kf + 8 * g);
      const float4 f1 = *(const float4*)(qg + 32 * kf + 8 * g + 4);
      union { unsigned short us[8]; short8 s8; } qa;
      qa.us[0] = (unsigned short)bf_bits(f0.x * QSCALE);
      qa.us[1] = (unsigned short)bf_bits(f0.y * QSCALE);
      qa.us[2] = (unsigned short)bf_bits(f0.z * QSCALE);
      qa.us[3] = (unsigned short)bf_bits(f0.w * QSCALE);
      qa.us[4] = (unsigned short)bf_bits(f1.x * QSCALE);
      qa.us[5] = (unsigned short)bf_bits(f1.y * QSCALE);
      qa.us[6] = (unsigned short)bf_bits(f1.z * QSCALE);
      qa.us[7] = (unsigned short)bf_bits(f1.w * QSCALE);
      qf[kf] = as_bf16x8(qa.s8);
    }
  }

  f32x4 acc[8] = {};
  float m_run = -3.0e38f;
  float ssum  = 0.f;
  const int swz = (m15 & 7) << 4;  // XOR swizzle for LDS reads (row&7 == m15&7 for K and V^T)

  short8 kreg[2], vreg[2];
  const short8* gK = (const short8*)(Kb + (size_t)n * T_SEQ * DH);   // [2048][16] short8
  const short8* gV = (const short8*)(Vt + (size_t)n * DH * T_SEQ);   // [128][256] short8

  auto loadRegs = [&](int kt) {
    const int t0 = kt * BKV;
    #pragma unroll
    for (int i = 0; i < 2; ++i) {                 // K: wave w stages rows 8w..8w+7, 16B chunk = m15
      int row = 8 * w + 4 * i + g;
      kreg[i] = gK[(size_t)(t0 + row) * 16 + m15];
    }
    #pragma unroll
    for (int i = 0; i < 2; ++i) {                 // V^T: wave w stages d 16w..16w+15, chunk = lane&7
      int d = 16 * w + 8 * i + (lane >> 3);
      vreg[i] = gV[(size_t)d * 256 + (t0 >> 3) + (lane & 7)];
    }
  };
  auto writeRegs = [&]() {                        // swizzled ds_write_b128, single buffer
    #pragma unroll
    for (int i = 0; i < 2; ++i) {
      int row = 8 * w + 4 * i + g;
      int off = row * 256 + ((m15 * 16) ^ ((row & 7) << 4));
      *(short8*)(smem + off) = kreg[i];
    }
    #pragma unroll
    for (int i = 0; i < 2; ++i) {
      int d = 16 * w + 8 * i + (lane >> 3);
      int off = 16384 + d * 128 + (((lane & 7) * 16) ^ ((d & 7) << 4));
      *(short8*)(smem + off) = vreg[i];
    }
  };

  loadRegs(k0);
  writeRegs();

  for (int kt = k0; kt < k1; ++kt) {
    __syncthreads();                              // tile kt visible in LDS
    if (kt + 1 < k1) loadRegs(kt + 1);            // issue next-tile global loads early

    const char* kb = smem;
    const char* vb = smem + 16384;

    // ---- S^T[64 kv][16 q] = K_tile * Q^T ----
    f32x4 s[4] = {};
    __builtin_amdgcn_s_setprio(1);
    #pragma unroll
    for (int kf = 0; kf < 4; ++kf) {
      #pragma unroll
      for (int ma = 0; ma < 4; ++ma) {
        short8 kfr = *(const short8*)(kb + (16 * ma + m15) * 256 + ((g * 16 + 64 * kf) ^ swz));
        s[ma] = __builtin_amdgcn_mfma_f32_16x16x32_bf16(as_bf16x8(kfr), qf[kf], s[ma], 0, 0, 0);
      }
    }
    __builtin_amdgcn_s_setprio(0);

    if (masked && kt >= 2 * Q) {                  // last-two tiles: causal mask
      #pragma unroll
      for (int ma = 0; ma < 4; ++ma)
        #pragma unroll
        for (int rr = 0; rr < 4; ++rr) {
          int kvg = kt * BKV + ma * 16 + g * 4 + rr;
          if (kvg > qrow) s[ma][rr] = -1.0e30f;
        }
    }

    // ---- online softmax (exp2 domain); row q = m15 lives on lanes {q, q+16, q+32, q+48} ----
    float mx = s[0][0];
    #pragma unroll
    for (int ma = 0; ma < 4; ++ma)
      #pragma unroll
      for (int rr = 0; rr < 4; ++rr) mx = fmaxf(mx, s[ma][rr]);
    mx = fmaxf(mx, __shfl_xor(mx, 16));
    mx = fmaxf(mx, __shfl_xor(mx, 32));
    float mnew = fmaxf(m_run, mx);
    float corr = exp2f(m_run - mnew);

    float p[4][4];
    float lsum = 0.f;
    #pragma unroll
    for (int ma = 0; ma < 4; ++ma)
      #pragma unroll
      for (int rr = 0; rr < 4; ++rr) { p[ma][rr] = exp2f(s[ma][rr] - mnew); lsum += p[ma][rr]; }
    lsum += __shfl_xor(lsum, 16);
    lsum += __shfl_xor(lsum, 32);
    ssum = ssum * corr + lsum;
    m_run = mnew;
    #pragma unroll
    for (int i = 0; i < 8; ++i) {
      acc[i][0] *= corr; acc[i][1] *= corr; acc[i][2] *= corr; acc[i][3] *= corr;
    }

    // ---- pack P^T to bf16 pairs: u[ma][wd] = (p[ma][2wd], p[ma][2wd+1]) ----
    uint32_t u[4][2];
    #pragma unroll
    for (int ma = 0; ma < 4; ++ma) {
      u[ma][0] = bf_bits(p[ma][0]) | (bf_bits(p[ma][1]) << 16);
      u[ma][1] = bf_bits(p[ma][2]) | (bf_bits(p[ma][3]) << 16);
    }

    // ---- redistribute to B-frag layout: lane needs P^T[kv=32ks+8g+j][q=m15] ----
    // holder(kv): lane ((kv&15)>>2)*16 + q, value u[kv>>4][(kv&3)>>1]. For fixed (ks,g):
    // ma' = 2ks + (g>>1); j=0..3 from srcA = ((g&1)<<5)+q, j=4..7 from srcA+16.
    const int srcA = ((g & 1) << 5) + m15;
    const int sel  = g >> 1;
    bf16x8 pfr[2];
    #pragma unroll
    for (int ks = 0; ks < 2; ++ks) {
      uint32_t a00 = (uint32_t)__shfl((int)u[2 * ks + 0][0], srcA);
      uint32_t a01 = (uint32_t)__shfl((int)u[2 * ks + 0][1], srcA);
      uint32_t a10 = (uint32_t)__shfl((int)u[2 * ks + 1][0], srcA);
      uint32_t a11 = (uint32_t)__shfl((int)u[2 * ks + 1][1], srcA);
      uint32_t b00 = (uint32_t)__shfl((int)u[2 * ks + 0][0], srcA + 16);
      uint32_t b01 = (uint32_t)__shfl((int)u[2 * ks + 0][1], srcA + 16);
      uint32_t b10 = (uint32_t)__shfl((int)u[2 * ks + 1][0], srcA + 16);
      uint32_t b11 = (uint32_t)__shfl((int)u[2 * ks + 1][1], srcA + 16);
      union { uint32_t q[4]; short8 s8; } pu;
      pu.q[0] = sel ? a10 : a00;
      pu.q[1] = sel ? a11 : a01;
      pu.q[2] = sel ? b10 : b00;
      pu.q[3] = sel ? b11 : b01;
      pfr[ks] = as_bf16x8(pu.s8);
    }

    // ---- O^T[128 d][16 q] += V^T_tile * P^T ----
    __builtin_amdgcn_s_setprio(1);
    #pragma unroll
    for (int dsub = 0; dsub < 8; ++dsub) {
      #pragma unroll
      for (int ks = 0; ks < 2; ++ks) {
        short8 vfr = *(const short8*)(vb + (16 * dsub + m15) * 128 + ((g * 16 + 64 * ks) ^ swz));
        acc[dsub] = __builtin_amdgcn_mfma_f32_16x16x32_bf16(as_bf16x8(vfr), pfr[ks], acc[dsub], 0, 0, 0);
      }
    }
    __builtin_amdgcn_s_setprio(0);

    __syncthreads();                              // all waves done reading LDS tile kt
    if (kt + 1 < k1) writeRegs();                 // stage tile kt+1
  }

  if (nc == 1) {
    // single chunk: final result, normalize and write Out
    const float inv = 1.0f / ssum;
    float* ob = Out + ((size_t)n * T_SEQ + qrow) * DH;
    #pragma unroll
    for (int dsub = 0; dsub < 8; ++dsub) {
      f32x4 o;
      o[0] = acc[dsub][0] * inv; o[1] = acc[dsub][1] * inv;
      o[2] = acc[dsub][2] * inv; o[3] = acc[dsub][3] * inv;
      *(f32x4*)(ob + dsub * 16 + g * 4) = o;
    }
  } else {
    // partial slot (tight pack over Q>=4): slot = n*36 + b8 + c, b8 = sum_{4<=Q'<Q} nc(Q')
    int b8 = 0;
    for (int qq = 4; qq < Q; ++qq) b8 += (2 * qq + 9) >> 3;
    float* slot = Part + ((size_t)n * 36 + b8 + c) * SLOT_F;
    const int qr = 16 * w + m15;
    if (g == 0) { slot[qr] = m_run; slot[128 + qr] = ssum; }
    float* so = slot + 256 + (size_t)qr * 128;
    #pragma unroll
    for (int dsub = 0; dsub < 8; ++dsub)
      *(f32x4*)(so + dsub * 16 + 4 * g) = acc[dsub];
  }
}

// ---------------- combine partial chunks (masked split path only) ----------------
__global__ void combine_kernel(const float* __restrict__ Part, float* __restrict__ Out,
                               const int* __restrict__ maskp, int use_split) {
  if (!maskp[0] || !use_split) return;
  const int cb = blockIdx.x;                      // 0..191
  const int n  = cb & 15;
  const int Q  = (cb >> 4) + 4;
  const int nc = (2 * Q + 9) >> 3;                // 2..4
  int b8 = 0;
  for (int qq = 4; qq < Q; ++qq) b8 += (2 * qq + 9) >> 3;
  const float* slot0 = Part + ((size_t)n * 36 + b8) * SLOT_F;

  const int tid = threadIdx.x;
  const int q   = tid >> 1;                       // 0..127
  const int d0  = (tid & 1) * 64;

  float m[4], s[4], wgt[4];
  float M = -3.0e38f;
  for (int i = 0; i < nc; ++i) {
    m[i] = slot0[(size_t)i * SLOT_F + q];
    s[i] = slot0[(size_t)i * SLOT_F + 128 + q];
    M = fmaxf(M, m[i]);
  }
  float denom = 0.f;
  for (int i = 0; i < nc; ++i) { wgt[i] = exp2f(m[i] - M); denom += s[i] * wgt[i]; }
  const float inv = 1.0f / denom;

  float* ob = Out + ((size_t)n * T_SEQ + Q * 128 + q) * DH + d0;
  #pragma unroll
  for (int j = 0; j < 16; ++j) {
    f32x4 a = {};
    for (int i = 0; i < nc; ++i) {
      const f32x4 v = *(const f32x4*)(slot0 + (size_t)i * SLOT_F + 256 + (size_t)q * 128 + d0 + 4 * j);
      a[0] += v[0] * wgt[i]; a[1] += v[1] * wgt[i]; a[2] += v[2] * wgt[i]; a[3] += v[3] * wgt[i];
    }
    a[0] *= inv; a[1] *= inv; a[2] *= inv; a[3] *= inv;
    *(f32x4*)(ob + 4 * j) = a;
  }
}

extern "C" void kernel_launch(void* const* d_in, const int* in_sizes, int n_in,
                              void* d_out, int out_size, void* d_ws, size_t ws_size,
                              hipStream_t stream) {
  (void)in_sizes; (void)n_in; (void)out_size;
  const float* q = (const float*)d_in[0];
  const float* k = (const float*)d_in[1];
  const float* v = (const float*)d_in[2];
  const int* maskp = (const int*)d_in[3];
  float* out = (float*)d_out;

  const size_t elems = (size_t)16 * T_SEQ * DH;   // 4,194,304 per tensor
  unsigned short* Kb = (unsigned short*)d_ws;     // 8MB
  unsigned short* Vt = Kb + elems;                // 8MB
  float* Part = (float*)d_ws + elems;             // after 16MB: 576 slots * 16640 f32 = 38.3MB
  const int use_split = (ws_size >= WS_NEEDED) ? 1 : 0;

  prep_kv<<<dim3(320, 16), 256, 0, stream>>>(k, v, Kb, Vt);
  attn_fwd<<<dim3(640), 512, 0, stream>>>(q, Kb, Vt, out, Part, maskp, use_split);
  combine_kernel<<<dim3(192), 256, 0, stream>>>(Part, out, maskp, use_split);
}

// Round 7
// 162.372 us; speedup vs baseline: 1.4466x; 1.4466x over previous
//
#include <hip/hip_runtime.h>
#include <hip/hip_bf16.h>
#include <stdint.h>

#define T_SEQ 2048
#define DH    128
#define BKV   64
#define QSCALE 0.12751742796f   // (1/sqrt(128)) * log2(e): exp2-domain softmax
#define SLOT_F 16640             // partial slot: m[128], s[128], O[128][128] floats
#define WS_NEEDED 55115776ULL    // 16.8MB bf16 K/V^T + 38.3MB partials (576 slots)

typedef short  short8 __attribute__((ext_vector_type(8)));
typedef __bf16 bf16x8 __attribute__((ext_vector_type(8)));
typedef float  f32x4  __attribute__((ext_vector_type(4)));

__device__ __forceinline__ bf16x8 as_bf16x8(short8 x) { return __builtin_bit_cast(bf16x8, x); }

__device__ __forceinline__ uint32_t bf_bits(float x) {
  union { __hip_bfloat16 h; unsigned short u; } cv;
  cv.h = __float2bfloat16(x);
  return (uint32_t)cv.u;
}

// ---------------- merged pre-pass: K fp32->bf16, V[n][t][d] -> Vt[n][d][t] bf16 ----------------
// grid (320, 16), 256 threads. x<256: K convert (65536 float4 per n). x>=256: V 64x64 transpose tile.
__global__ void prep_kv(const float* __restrict__ k, const float* __restrict__ v,
                        unsigned short* __restrict__ kb, unsigned short* __restrict__ vt) {
  __shared__ float tile[64][65];
  const int n = blockIdx.y, x = blockIdx.x, tid = threadIdx.x;
  if (x < 256) {
    const int i = (n * 256 + x) * 256 + tid;     // float4 index into K
    const float4 f = ((const float4*)k)[i];
    union { unsigned short us[4]; uint2 u2; } o;
    o.us[0] = (unsigned short)bf_bits(f.x);
    o.us[1] = (unsigned short)bf_bits(f.y);
    o.us[2] = (unsigned short)bf_bits(f.z);
    o.us[3] = (unsigned short)bf_bits(f.w);
    ((uint2*)kb)[i] = o.u2;
  } else {
    const int x2 = x - 256;
    const int t0 = (x2 & 31) * 64, d0 = (x2 >> 5) * 64;
    const int tx = tid & 63, ty = tid >> 6;      // (64, 4)
    #pragma unroll
    for (int i = 0; i < 64; i += 4)
      tile[ty + i][tx] = v[((size_t)n * T_SEQ + t0 + ty + i) * DH + d0 + tx];
    __syncthreads();
    #pragma unroll
    for (int i = 0; i < 64; i += 4)
      vt[((size_t)n * DH + d0 + ty + i) * T_SEQ + t0 + tx] = (unsigned short)bf_bits(tile[tx][ty + i]);
  }
}

// ---------------- flash attention fwd (causal), bf16 MFMA, 8-wave blocks, uniform KV-chunks ----------------
// Block = one job (n, Q, chunk c): 128 q-rows (wave w owns rows Q*128+16w..+15), KV tiles
// kt in [8c, min(8c+8, 2Q+2)). 8 waves share one 32KB K/V LDS tile -> wave-level overlap of
// softmax chains with MFMAs. Single-chunk q-blocks write Out directly; split blocks write
// unnormalized (m, s, O) partials, merged by combine_kernel. use_split=0 falls back to one
// job per q-block.
// __launch_bounds__(512, 4): VGPR cap 128 (R6's (512,6) capped ~85 -> acc/qf spilled to
// scratch, 425MB/dispatch HBM traffic, 128us. Guideline 6.)
// S^T = mfma(A=K_tile, B=Q): lane holds S for q = lane&15, kv = 16*ma + 4*(lane>>4) + reg.
// O^T = mfma(A=V^T_tile, B=P^T): lane holds O for q = lane&15, d = 16*dsub + 4*(lane>>4) + reg.
// Fragment layout (HW-verified, m97/m89): A/B lane l <-> [l&15][(l>>4)*8+j]; C/D col=l&15, row=(l>>4)*4+reg.
__global__ __launch_bounds__(512, 4) void attn_fwd(
    const float* __restrict__ Qf,
    const unsigned short* __restrict__ Kb,
    const unsigned short* __restrict__ Vt,
    float* __restrict__ Out,
    float* __restrict__ Part,
    const int* __restrict__ maskp,
    int use_split)
{
  __shared__ __align__(16) char smem[32768];  // K tile @0 (16KB), V^T tile @16384 (16KB)

  const int tid  = threadIdx.x;
  const int lane = tid & 63;
  const int w    = tid >> 6;                  // 0..7
  const int m15  = lane & 15;
  const int g    = lane >> 4;

  // XCD L2 affinity: XCD = bid%8 serves n in {r, r+8} (2MB K+V bf16 < 4MB per-XCD L2).
  const int bid = blockIdx.x;
  const int n   = (bid & 7) + 8 * ((bid >> 3) & 1);
  const int job = bid >> 4;                    // 0..39
  const int masked = maskp[0];

  int Q, c, k0, k1, nc;
  if (masked && use_split) {
    // jobs enumerate (Q, chunk): tiles(Q) = 2Q+2, nc(Q) = ceil((2Q+2)/8) = (2Q+9)>>3; sum = 40.
    int base = 0; Q = 0;
    for (;;) { int ncq = (2 * Q + 9) >> 3; if (job < base + ncq) { c = job - base; break; } base += ncq; ++Q; }
    nc = (2 * Q + 9) >> 3;
    k0 = c * 8;
    k1 = min(k0 + 8, 2 * Q + 2);
  } else {
    if (job >= 16) return;                     // fallback / unmasked: one job per q-block
    Q = job; c = 0; nc = 1; k0 = 0;
    k1 = masked ? (2 * Q + 2) : (T_SEQ / BKV);
  }

  const int qrow = Q * 128 + 16 * w + m15;

  // Q B-fragments, fp32 -> bf16 in-kernel with scale*log2e folded:
  // lane needs Q[q-row][k = 32*kf + 8*g + j], j=0..7.
  bf16x8 qf[4];
  {
    const float* qg = Qf + ((size_t)n * T_SEQ + qrow) * DH;
    #pragma unroll
    for (int kf = 0; kf < 4; ++kf) {
      const float4 f0 = *(const float4*)(qg + 32 * kf + 8 * g);
      const float4 f1 = *(const float4*)(qg + 32 * kf + 8 * g + 4);
      union { unsigned short us[8]; short8 s8; } qa;
      qa.us[0] = (unsigned short)bf_bits(f0.x * QSCALE);
      qa.us[1] = (unsigned short)bf_bits(f0.y * QSCALE);
      qa.us[2] = (unsigned short)bf_bits(f0.z * QSCALE);
      qa.us[3] = (unsigned short)bf_bits(f0.w * QSCALE);
      qa.us[4] = (unsigned short)bf_bits(f1.x * QSCALE);
      qa.us[5] = (unsigned short)bf_bits(f1.y * QSCALE);
      qa.us[6] = (unsigned short)bf_bits(f1.z * QSCALE);
      qa.us[7] = (unsigned short)bf_bits(f1.w * QSCALE);
      qf[kf] = as_bf16x8(qa.s8);
    }
  }

  f32x4 acc[8] = {};
  float m_run = -3.0e38f;
  float ssum  = 0.f;
  const int swz = (m15 & 7) << 4;  // XOR swizzle for LDS reads (row&7 == m15&7 for K and V^T)

  short8 kreg[2], vreg[2];
  const short8* gK = (const short8*)(Kb + (size_t)n * T_SEQ * DH);   // [2048][16] short8
  const short8* gV = (const short8*)(Vt + (size_t)n * DH * T_SEQ);   // [128][256] short8

  auto loadRegs = [&](int kt) {
    const int t0 = kt * BKV;
    #pragma unroll
    for (int i = 0; i < 2; ++i) {                 // K: wave w stages rows 8w..8w+7, 16B chunk = m15
      int row = 8 * w + 4 * i + g;
      kreg[i] = gK[(size_t)(t0 + row) * 16 + m15];
    }
    #pragma unroll
    for (int i = 0; i < 2; ++i) {                 // V^T: wave w stages d 16w..16w+15, chunk = lane&7
      int d = 16 * w + 8 * i + (lane >> 3);
      vreg[i] = gV[(size_t)d * 256 + (t0 >> 3) + (lane & 7)];
    }
  };
  auto writeRegs = [&]() {                        // swizzled ds_write_b128, single buffer
    #pragma unroll
    for (int i = 0; i < 2; ++i) {
      int row = 8 * w + 4 * i + g;
      int off = row * 256 + ((m15 * 16) ^ ((row & 7) << 4));
      *(short8*)(smem + off) = kreg[i];
    }
    #pragma unroll
    for (int i = 0; i < 2; ++i) {
      int d = 16 * w + 8 * i + (lane >> 3);
      int off = 16384 + d * 128 + (((lane & 7) * 16) ^ ((d & 7) << 4));
      *(short8*)(smem + off) = vreg[i];
    }
  };

  loadRegs(k0);
  writeRegs();

  for (int kt = k0; kt < k1; ++kt) {
    __syncthreads();                              // tile kt visible in LDS
    if (kt + 1 < k1) loadRegs(kt + 1);            // issue next-tile global loads early

    const char* kb = smem;
    const char* vb = smem + 16384;

    // ---- S^T[64 kv][16 q] = K_tile * Q^T ----
    f32x4 s[4] = {};
    __builtin_amdgcn_s_setprio(1);
    #pragma unroll
    for (int kf = 0; kf < 4; ++kf) {
      #pragma unroll
      for (int ma = 0; ma < 4; ++ma) {
        short8 kfr = *(const short8*)(kb + (16 * ma + m15) * 256 + ((g * 16 + 64 * kf) ^ swz));
        s[ma] = __builtin_amdgcn_mfma_f32_16x16x32_bf16(as_bf16x8(kfr), qf[kf], s[ma], 0, 0, 0);
      }
    }
    __builtin_amdgcn_s_setprio(0);

    if (masked && kt >= 2 * Q) {                  // last-two tiles: causal mask
      #pragma unroll
      for (int ma = 0; ma < 4; ++ma)
        #pragma unroll
        for (int rr = 0; rr < 4; ++rr) {
          int kvg = kt * BKV + ma * 16 + g * 4 + rr;
          if (kvg > qrow) s[ma][rr] = -1.0e30f;
        }
    }

    // ---- online softmax (exp2 domain); row q = m15 lives on lanes {q, q+16, q+32, q+48} ----
    float mx = s[0][0];
    #pragma unroll
    for (int ma = 0; ma < 4; ++ma)
      #pragma unroll
      for (int rr = 0; rr < 4; ++rr) mx = fmaxf(mx, s[ma][rr]);
    mx = fmaxf(mx, __shfl_xor(mx, 16));
    mx = fmaxf(mx, __shfl_xor(mx, 32));
    float mnew = fmaxf(m_run, mx);
    float corr = exp2f(m_run - mnew);

    float p[4][4];
    float lsum = 0.f;
    #pragma unroll
    for (int ma = 0; ma < 4; ++ma)
      #pragma unroll
      for (int rr = 0; rr < 4; ++rr) { p[ma][rr] = exp2f(s[ma][rr] - mnew); lsum += p[ma][rr]; }
    lsum += __shfl_xor(lsum, 16);
    lsum += __shfl_xor(lsum, 32);
    ssum = ssum * corr + lsum;
    m_run = mnew;
    #pragma unroll
    for (int i = 0; i < 8; ++i) {
      acc[i][0] *= corr; acc[i][1] *= corr; acc[i][2] *= corr; acc[i][3] *= corr;
    }

    // ---- pack P^T to bf16 pairs: u[ma][wd] = (p[ma][2wd], p[ma][2wd+1]) ----
    uint32_t u[4][2];
    #pragma unroll
    for (int ma = 0; ma < 4; ++ma) {
      u[ma][0] = bf_bits(p[ma][0]) | (bf_bits(p[ma][1]) << 16);
      u[ma][1] = bf_bits(p[ma][2]) | (bf_bits(p[ma][3]) << 16);
    }

    // ---- redistribute to B-frag layout: lane needs P^T[kv=32ks+8g+j][q=m15] ----
    // holder(kv): lane ((kv&15)>>2)*16 + q, value u[kv>>4][(kv&3)>>1]. For fixed (ks,g):
    // ma' = 2ks + (g>>1); j=0..3 from srcA = ((g&1)<<5)+q, j=4..7 from srcA+16.
    const int srcA = ((g & 1) << 5) + m15;
    const int sel  = g >> 1;
    bf16x8 pfr[2];
    #pragma unroll
    for (int ks = 0; ks < 2; ++ks) {
      uint32_t a00 = (uint32_t)__shfl((int)u[2 * ks + 0][0], srcA);
      uint32_t a01 = (uint32_t)__shfl((int)u[2 * ks + 0][1], srcA);
      uint32_t a10 = (uint32_t)__shfl((int)u[2 * ks + 1][0], srcA);
      uint32_t a11 = (uint32_t)__shfl((int)u[2 * ks + 1][1], srcA);
      uint32_t b00 = (uint32_t)__shfl((int)u[2 * ks + 0][0], srcA + 16);
      uint32_t b01 = (uint32_t)__shfl((int)u[2 * ks + 0][1], srcA + 16);
      uint32_t b10 = (uint32_t)__shfl((int)u[2 * ks + 1][0], srcA + 16);
      uint32_t b11 = (uint32_t)__shfl((int)u[2 * ks + 1][1], srcA + 16);
      union { uint32_t q[4]; short8 s8; } pu;
      pu.q[0] = sel ? a10 : a00;
      pu.q[1] = sel ? a11 : a01;
      pu.q[2] = sel ? b10 : b00;
      pu.q[3] = sel ? b11 : b01;
      pfr[ks] = as_bf16x8(pu.s8);
    }

    // ---- O^T[128 d][16 q] += V^T_tile * P^T ----
    __builtin_amdgcn_s_setprio(1);
    #pragma unroll
    for (int dsub = 0; dsub < 8; ++dsub) {
      #pragma unroll
      for (int ks = 0; ks < 2; ++ks) {
        short8 vfr = *(const short8*)(vb + (16 * dsub + m15) * 128 + ((g * 16 + 64 * ks) ^ swz));
        acc[dsub] = __builtin_amdgcn_mfma_f32_16x16x32_bf16(as_bf16x8(vfr), pfr[ks], acc[dsub], 0, 0, 0);
      }
    }
    __builtin_amdgcn_s_setprio(0);

    __syncthreads();                              // all waves done reading LDS tile kt
    if (kt + 1 < k1) writeRegs();                 // stage tile kt+1
  }

  if (nc == 1) {
    // single chunk: final result, normalize and write Out
    const float inv = 1.0f / ssum;
    float* ob = Out + ((size_t)n * T_SEQ + qrow) * DH;
    #pragma unroll
    for (int dsub = 0; dsub < 8; ++dsub) {
      f32x4 o;
      o[0] = acc[dsub][0] * inv; o[1] = acc[dsub][1] * inv;
      o[2] = acc[dsub][2] * inv; o[3] = acc[dsub][3] * inv;
      *(f32x4*)(ob + dsub * 16 + g * 4) = o;
    }
  } else {
    // partial slot (tight pack over Q>=4): slot = n*36 + b8 + c, b8 = sum_{4<=Q'<Q} nc(Q')
    int b8 = 0;
    for (int qq = 4; qq < Q; ++qq) b8 += (2 * qq + 9) >> 3;
    float* slot = Part + ((size_t)n * 36 + b8 + c) * SLOT_F;
    const int qr = 16 * w + m15;
    if (g == 0) { slot[qr] = m_run; slot[128 + qr] = ssum; }
    float* so = slot + 256 + (size_t)qr * 128;
    #pragma unroll
    for (int dsub = 0; dsub < 8; ++dsub)
      *(f32x4*)(so + dsub * 16 + 4 * g) = acc[dsub];
  }
}

// ---------------- combine partial chunks (masked split path only) ----------------
__global__ void combine_kernel(const float* __restrict__ Part, float* __restrict__ Out,
                               const int* __restrict__ maskp, int use_split) {
  if (!maskp[0] || !use_split) return;
  const int cb = blockIdx.x;                      // 0..191
  const int n  = cb & 15;
  const int Q  = (cb >> 4) + 4;
  const int nc = (2 * Q + 9) >> 3;                // 2..4
  int b8 = 0;
  for (int qq = 4; qq < Q; ++qq) b8 += (2 * qq + 9) >> 3;
  const float* slot0 = Part + ((size_t)n * 36 + b8) * SLOT_F;

  const int tid = threadIdx.x;
  const int q   = tid >> 1;                       // 0..127
  const int d0  = (tid & 1) * 64;

  float m[4], s[4], wgt[4];
  float M = -3.0e38f;
  for (int i = 0; i < nc; ++i) {
    m[i] = slot0[(size_t)i * SLOT_F + q];
    s[i] = slot0[(size_t)i * SLOT_F + 128 + q];
    M = fmaxf(M, m[i]);
  }
  float denom = 0.f;
  for (int i = 0; i < nc; ++i) { wgt[i] = exp2f(m[i] - M); denom += s[i] * wgt[i]; }
  const float inv = 1.0f / denom;

  float* ob = Out + ((size_t)n * T_SEQ + Q * 128 + q) * DH + d0;
  #pragma unroll
  for (int j = 0; j < 16; ++j) {
    f32x4 a = {};
    for (int i = 0; i < nc; ++i) {
      const f32x4 v = *(const f32x4*)(slot0 + (size_t)i * SLOT_F + 256 + (size_t)q * 128 + d0 + 4 * j);
      a[0] += v[0] * wgt[i]; a[1] += v[1] * wgt[i]; a[2] += v[2] * wgt[i]; a[3] += v[3] * wgt[i];
    }
    a[0] *= inv; a[1] *= inv; a[2] *= inv; a[3] *= inv;
    *(f32x4*)(ob + 4 * j) = a;
  }
}

extern "C" void kernel_launch(void* const* d_in, const int* in_sizes, int n_in,
                              void* d_out, int out_size, void* d_ws, size_t ws_size,
                              hipStream_t stream) {
  (void)in_sizes; (void)n_in; (void)out_size;
  const float* q = (const float*)d_in[0];
  const float* k = (const float*)d_in[1];
  const float* v = (const float*)d_in[2];
  const int* maskp = (const int*)d_in[3];
  float* out = (float*)d_out;

  const size_t elems = (size_t)16 * T_SEQ * DH;   // 4,194,304 per tensor
  unsigned short* Kb = (unsigned short*)d_ws;     // 8MB
  unsigned short* Vt = Kb + elems;                // 8MB
  float* Part = (float*)d_ws + elems;             // after 16MB: 576 slots * 16640 f32 = 38.3MB
  const int use_split = (ws_size >= WS_NEEDED) ? 1 : 0;

  prep_kv<<<dim3(320, 16), 256, 0, stream>>>(k, v, Kb, Vt);
  attn_fwd<<<dim3(640), 512, 0, stream>>>(q, Kb, Vt, out, Part, maskp, use_split);
  combine_kernel<<<dim3(192), 256, 0, stream>>>(Part, out, maskp, use_split);
}

// Round 8
// 160.362 us; speedup vs baseline: 1.4647x; 1.0125x over previous
//
#include <hip/hip_runtime.h>
#include <hip/hip_bf16.h>
#include <stdint.h>

#define T_SEQ 2048
#define DH    128
#define BKV   64
#define QSCALE 0.12751742796f   // (1/sqrt(128)) * log2(e): exp2-domain softmax
#define SLOT_F 16640             // partial slot: m[128], s[128], O[128][128] floats
#define WS_NEEDED 55115776ULL    // 16.8MB bf16 K/V^T + 38.3MB partials (576 slots)

typedef short  short8 __attribute__((ext_vector_type(8)));
typedef __bf16 bf16x8 __attribute__((ext_vector_type(8)));
typedef float  f32x4  __attribute__((ext_vector_type(4)));

__device__ __forceinline__ bf16x8 as_bf16x8(short8 x) { return __builtin_bit_cast(bf16x8, x); }

__device__ __forceinline__ uint32_t bf_bits(float x) {
  union { __hip_bfloat16 h; unsigned short u; } cv;
  cv.h = __float2bfloat16(x);
  return (uint32_t)cv.u;
}

// ---------------- merged pre-pass: K fp32->bf16, V[n][t][d] -> Vt[n][d][t] bf16 ----------------
// grid (320, 16), 256 threads. x<256: K convert (65536 float4 per n). x>=256: V 64x64 transpose tile.
__global__ void prep_kv(const float* __restrict__ k, const float* __restrict__ v,
                        unsigned short* __restrict__ kb, unsigned short* __restrict__ vt) {
  __shared__ float tile[64][65];
  const int n = blockIdx.y, x = blockIdx.x, tid = threadIdx.x;
  if (x < 256) {
    const int i = (n * 256 + x) * 256 + tid;     // float4 index into K
    const float4 f = ((const float4*)k)[i];
    union { unsigned short us[4]; uint2 u2; } o;
    o.us[0] = (unsigned short)bf_bits(f.x);
    o.us[1] = (unsigned short)bf_bits(f.y);
    o.us[2] = (unsigned short)bf_bits(f.z);
    o.us[3] = (unsigned short)bf_bits(f.w);
    ((uint2*)kb)[i] = o.u2;
  } else {
    const int x2 = x - 256;
    const int t0 = (x2 & 31) * 64, d0 = (x2 >> 5) * 64;
    const int tx = tid & 63, ty = tid >> 6;      // (64, 4)
    #pragma unroll
    for (int i = 0; i < 64; i += 4)
      tile[ty + i][tx] = v[((size_t)n * T_SEQ + t0 + ty + i) * DH + d0 + tx];
    __syncthreads();
    #pragma unroll
    for (int i = 0; i < 64; i += 4)
      vt[((size_t)n * DH + d0 + ty + i) * T_SEQ + t0 + tx] = (unsigned short)bf_bits(tile[tx][ty + i]);
  }
}

// ---------------- flash attention fwd (causal), bf16 MFMA, 8-wave blocks, uniform KV-chunks ----------------
// Block = one job (n, Q, chunk c): 128 q-rows (wave w owns rows Q*128+16w..+15), KV tiles
// kt in [8c, min(8c+8, 2Q+2)). 8 waves share one K/V LDS tile -> wave-level overlap of
// softmax chains with MFMAs. DOUBLE-BUFFERED LDS (64KB), ONE barrier per tile (R2-verified
// loop shape): barrier -> issue loads kt+1 -> compute kt -> ds_write kt+1 into other buf.
// Defer-max (T13): skip acc rescale while max grows < 8 (exp2 values bounded by 2^8, safe).
// Single-chunk q-blocks write Out directly; split blocks write unnormalized (m, s, O)
// partials, merged by combine_kernel. use_split=0 falls back to one job per q-block.
// __launch_bounds__(512, 4): VGPR cap 128 (R6's (512,6) caused spill catastrophe).
// S^T = mfma(A=K_tile, B=Q): lane holds S for q = lane&15, kv = 16*ma + 4*(lane>>4) + reg.
// O^T = mfma(A=V^T_tile, B=P^T): lane holds O for q = lane&15, d = 16*dsub + 4*(lane>>4) + reg.
// Fragment layout (HW-verified, m97/m89): A/B lane l <-> [l&15][(l>>4)*8+j]; C/D col=l&15, row=(l>>4)*4+reg.
__global__ __launch_bounds__(512, 4) void attn_fwd(
    const float* __restrict__ Qf,
    const unsigned short* __restrict__ Kb,
    const unsigned short* __restrict__ Vt,
    float* __restrict__ Out,
    float* __restrict__ Part,
    const int* __restrict__ maskp,
    int use_split)
{
  __shared__ __align__(16) char smem[65536];  // K bufs @0,@16384; V^T bufs @32768,@49152

  const int tid  = threadIdx.x;
  const int lane = tid & 63;
  const int w    = tid >> 6;                  // 0..7
  const int m15  = lane & 15;
  const int g    = lane >> 4;

  // XCD L2 affinity: XCD = bid%8 serves n in {r, r+8} (2MB K+V bf16 < 4MB per-XCD L2).
  const int bid = blockIdx.x;
  const int n   = (bid & 7) + 8 * ((bid >> 3) & 1);
  const int job = bid >> 4;                    // 0..39
  const int masked = maskp[0];

  int Q, c, k0, k1, nc;
  if (masked && use_split) {
    // jobs enumerate (Q, chunk): tiles(Q) = 2Q+2, nc(Q) = ceil((2Q+2)/8) = (2Q+9)>>3; sum = 40.
    int base = 0; Q = 0;
    for (;;) { int ncq = (2 * Q + 9) >> 3; if (job < base + ncq) { c = job - base; break; } base += ncq; ++Q; }
    nc = (2 * Q + 9) >> 3;
    k0 = c * 8;
    k1 = min(k0 + 8, 2 * Q + 2);
  } else {
    if (job >= 16) return;                     // fallback / unmasked: one job per q-block
    Q = job; c = 0; nc = 1; k0 = 0;
    k1 = masked ? (2 * Q + 2) : (T_SEQ / BKV);
  }

  const int qrow = Q * 128 + 16 * w + m15;

  // Q B-fragments, fp32 -> bf16 in-kernel with scale*log2e folded:
  // lane needs Q[q-row][k = 32*kf + 8*g + j], j=0..7.
  bf16x8 qf[4];
  {
    const float* qg = Qf + ((size_t)n * T_SEQ + qrow) * DH;
    #pragma unroll
    for (int kf = 0; kf < 4; ++kf) {
      const float4 f0 = *(const float4*)(qg + 32 * kf + 8 * g);
      const float4 f1 = *(const float4*)(qg + 32 * kf + 8 * g + 4);
      union { unsigned short us[8]; short8 s8; } qa;
      qa.us[0] = (unsigned short)bf_bits(f0.x * QSCALE);
      qa.us[1] = (unsigned short)bf_bits(f0.y * QSCALE);
      qa.us[2] = (unsigned short)bf_bits(f0.z * QSCALE);
      qa.us[3] = (unsigned short)bf_bits(f0.w * QSCALE);
      qa.us[4] = (unsigned short)bf_bits(f1.x * QSCALE);
      qa.us[5] = (unsigned short)bf_bits(f1.y * QSCALE);
      qa.us[6] = (unsigned short)bf_bits(f1.z * QSCALE);
      qa.us[7] = (unsigned short)bf_bits(f1.w * QSCALE);
      qf[kf] = as_bf16x8(qa.s8);
    }
  }

  f32x4 acc[8] = {};
  float m_run = -3.0e38f;
  float ssum  = 0.f;
  const int swz = (m15 & 7) << 4;  // XOR swizzle for LDS reads (row&7 == m15&7 for K and V^T)

  short8 kreg[2], vreg[2];
  const short8* gK = (const short8*)(Kb + (size_t)n * T_SEQ * DH);   // [2048][16] short8
  const short8* gV = (const short8*)(Vt + (size_t)n * DH * T_SEQ);   // [128][256] short8

  auto loadRegs = [&](int kt) {
    const int t0 = kt * BKV;
    #pragma unroll
    for (int i = 0; i < 2; ++i) {                 // K: wave w stages rows 8w..8w+7, 16B chunk = m15
      int row = 8 * w + 4 * i + g;
      kreg[i] = gK[(size_t)(t0 + row) * 16 + m15];
    }
    #pragma unroll
    for (int i = 0; i < 2; ++i) {                 // V^T: wave w stages d 16w..16w+15, chunk = lane&7
      int d = 16 * w + 8 * i + (lane >> 3);
      vreg[i] = gV[(size_t)d * 256 + (t0 >> 3) + (lane & 7)];
    }
  };
  auto writeRegs = [&](int buf) {                 // swizzled ds_write_b128, double buffer
    #pragma unroll
    for (int i = 0; i < 2; ++i) {
      int row = 8 * w + 4 * i + g;
      int off = buf * 16384 + row * 256 + ((m15 * 16) ^ ((row & 7) << 4));
      *(short8*)(smem + off) = kreg[i];
    }
    #pragma unroll
    for (int i = 0; i < 2; ++i) {
      int d = 16 * w + 8 * i + (lane >> 3);
      int off = 32768 + buf * 16384 + d * 128 + (((lane & 7) * 16) ^ ((d & 7) << 4));
      *(short8*)(smem + off) = vreg[i];
    }
  };

  loadRegs(k0);
  writeRegs(k0 & 1);

  for (int kt = k0; kt < k1; ++kt) {
    __syncthreads();                              // tile kt visible; all reads of buf (kt+1)&1 done
    if (kt + 1 < k1) loadRegs(kt + 1);            // issue next-tile global loads early

    const char* kb = smem + (kt & 1) * 16384;
    const char* vb = smem + 32768 + (kt & 1) * 16384;

    // ---- S^T[64 kv][16 q] = K_tile * Q^T ----
    f32x4 s[4] = {};
    __builtin_amdgcn_s_setprio(1);
    #pragma unroll
    for (int kf = 0; kf < 4; ++kf) {
      #pragma unroll
      for (int ma = 0; ma < 4; ++ma) {
        short8 kfr = *(const short8*)(kb + (16 * ma + m15) * 256 + ((g * 16 + 64 * kf) ^ swz));
        s[ma] = __builtin_amdgcn_mfma_f32_16x16x32_bf16(as_bf16x8(kfr), qf[kf], s[ma], 0, 0, 0);
      }
    }
    __builtin_amdgcn_s_setprio(0);

    if (masked && kt >= 2 * Q) {                  // last-two tiles: causal mask
      #pragma unroll
      for (int ma = 0; ma < 4; ++ma)
        #pragma unroll
        for (int rr = 0; rr < 4; ++rr) {
          int kvg = kt * BKV + ma * 16 + g * 4 + rr;
          if (kvg > qrow) s[ma][rr] = -1.0e30f;
        }
    }

    // ---- online softmax (exp2 domain); row q = m15 lives on lanes {q, q+16, q+32, q+48} ----
    float mx = s[0][0];
    #pragma unroll
    for (int ma = 0; ma < 4; ++ma)
      #pragma unroll
      for (int rr = 0; rr < 4; ++rr) mx = fmaxf(mx, s[ma][rr]);
    mx = fmaxf(mx, __shfl_xor(mx, 16));
    mx = fmaxf(mx, __shfl_xor(mx, 32));

    // defer-max (T13): only rescale when some row's max grew by >8; P bounded by 2^8.
    if (!__all(mx <= m_run + 8.0f)) {
      float mnew = fmaxf(m_run, mx);
      float corr = exp2f(m_run - mnew);
      ssum *= corr;
      #pragma unroll
      for (int i = 0; i < 8; ++i) {
        acc[i][0] *= corr; acc[i][1] *= corr; acc[i][2] *= corr; acc[i][3] *= corr;
      }
      m_run = mnew;
    }

    float p[4][4];
    float lsum = 0.f;
    #pragma unroll
    for (int ma = 0; ma < 4; ++ma)
      #pragma unroll
      for (int rr = 0; rr < 4; ++rr) { p[ma][rr] = exp2f(s[ma][rr] - m_run); lsum += p[ma][rr]; }
    lsum += __shfl_xor(lsum, 16);
    lsum += __shfl_xor(lsum, 32);
    ssum += lsum;

    // ---- pack P^T to bf16 pairs: u[ma][wd] = (p[ma][2wd], p[ma][2wd+1]) ----
    uint32_t u[4][2];
    #pragma unroll
    for (int ma = 0; ma < 4; ++ma) {
      u[ma][0] = bf_bits(p[ma][0]) | (bf_bits(p[ma][1]) << 16);
      u[ma][1] = bf_bits(p[ma][2]) | (bf_bits(p[ma][3]) << 16);
    }

    // ---- redistribute to B-frag layout: lane needs P^T[kv=32ks+8g+j][q=m15] ----
    // holder(kv): lane ((kv&15)>>2)*16 + q, value u[kv>>4][(kv&3)>>1]. For fixed (ks,g):
    // ma' = 2ks + (g>>1); j=0..3 from srcA = ((g&1)<<5)+q, j=4..7 from srcA+16.
    const int srcA = ((g & 1) << 5) + m15;
    const int sel  = g >> 1;
    bf16x8 pfr[2];
    #pragma unroll
    for (int ks = 0; ks < 2; ++ks) {
      uint32_t a00 = (uint32_t)__shfl((int)u[2 * ks + 0][0], srcA);
      uint32_t a01 = (uint32_t)__shfl((int)u[2 * ks + 0][1], srcA);
      uint32_t a10 = (uint32_t)__shfl((int)u[2 * ks + 1][0], srcA);
      uint32_t a11 = (uint32_t)__shfl((int)u[2 * ks + 1][1], srcA);
      uint32_t b00 = (uint32_t)__shfl((int)u[2 * ks + 0][0], srcA + 16);
      uint32_t b01 = (uint32_t)__shfl((int)u[2 * ks + 0][1], srcA + 16);
      uint32_t b10 = (uint32_t)__shfl((int)u[2 * ks + 1][0], srcA + 16);
      uint32_t b11 = (uint32_t)__shfl((int)u[2 * ks + 1][1], srcA + 16);
      union { uint32_t q[4]; short8 s8; } pu;
      pu.q[0] = sel ? a10 : a00;
      pu.q[1] = sel ? a11 : a01;
      pu.q[2] = sel ? b10 : b00;
      pu.q[3] = sel ? b11 : b01;
      pfr[ks] = as_bf16x8(pu.s8);
    }

    // ---- O^T[128 d][16 q] += V^T_tile * P^T ----
    __builtin_amdgcn_s_setprio(1);
    #pragma unroll
    for (int dsub = 0; dsub < 8; ++dsub) {
      #pragma unroll
      for (int ks = 0; ks < 2; ++ks) {
        short8 vfr = *(const short8*)(vb + (16 * dsub + m15) * 128 + ((g * 16 + 64 * ks) ^ swz));
        acc[dsub] = __builtin_amdgcn_mfma_f32_16x16x32_bf16(as_bf16x8(vfr), pfr[ks], acc[dsub], 0, 0, 0);
      }
    }
    __builtin_amdgcn_s_setprio(0);

    if (kt + 1 < k1) writeRegs((kt + 1) & 1);     // stage tile kt+1 into the other buffer
  }

  if (nc == 1) {
    // single chunk: final result, normalize and write Out
    const float inv = 1.0f / ssum;
    float* ob = Out + ((size_t)n * T_SEQ + qrow) * DH;
    #pragma unroll
    for (int dsub = 0; dsub < 8; ++dsub) {
      f32x4 o;
      o[0] = acc[dsub][0] * inv; o[1] = acc[dsub][1] * inv;
      o[2] = acc[dsub][2] * inv; o[3] = acc[dsub][3] * inv;
      *(f32x4*)(ob + dsub * 16 + g * 4) = o;
    }
  } else {
    // partial slot (tight pack over Q>=4): slot = n*36 + b8 + c, b8 = sum_{4<=Q'<Q} nc(Q')
    int b8 = 0;
    for (int qq = 4; qq < Q; ++qq) b8 += (2 * qq + 9) >> 3;
    float* slot = Part + ((size_t)n * 36 + b8 + c) * SLOT_F;
    const int qr = 16 * w + m15;
    if (g == 0) { slot[qr] = m_run; slot[128 + qr] = ssum; }
    float* so = slot + 256 + (size_t)qr * 128;
    #pragma unroll
    for (int dsub = 0; dsub < 8; ++dsub)
      *(f32x4*)(so + dsub * 16 + 4 * g) = acc[dsub];
  }
}

// ---------------- combine partial chunks (masked split path only) ----------------
__global__ void combine_kernel(const float* __restrict__ Part, float* __restrict__ Out,
                               const int* __restrict__ maskp, int use_split) {
  if (!maskp[0] || !use_split) return;
  const int cb = blockIdx.x;                      // 0..191
  const int n  = cb & 15;
  const int Q  = (cb >> 4) + 4;
  const int nc = (2 * Q + 9) >> 3;                // 2..4
  int b8 = 0;
  for (int qq = 4; qq < Q; ++qq) b8 += (2 * qq + 9) >> 3;
  const float* slot0 = Part + ((size_t)n * 36 + b8) * SLOT_F;

  const int tid = threadIdx.x;
  const int q   = tid >> 1;                       // 0..127
  const int d0  = (tid & 1) * 64;

  float m[4], s[4], wgt[4];
  float M = -3.0e38f;
  for (int i = 0; i < nc; ++i) {
    m[i] = slot0[(size_t)i * SLOT_F + q];
    s[i] = slot0[(size_t)i * SLOT_F + 128 + q];
    M = fmaxf(M, m[i]);
  }
  float denom = 0.f;
  for (int i = 0; i < nc; ++i) { wgt[i] = exp2f(m[i] - M); denom += s[i] * wgt[i]; }
  const float inv = 1.0f / denom;

  float* ob = Out + ((size_t)n * T_SEQ + Q * 128 + q) * DH + d0;
  #pragma unroll
  for (int j = 0; j < 16; ++j) {
    f32x4 a = {};
    for (int i = 0; i < nc; ++i) {
      const f32x4 v = *(const f32x4*)(slot0 + (size_t)i * SLOT_F + 256 + (size_t)q * 128 + d0 + 4 * j);
      a[0] += v[0] * wgt[i]; a[1] += v[1] * wgt[i]; a[2] += v[2] * wgt[i]; a[3] += v[3] * wgt[i];
    }
    a[0] *= inv; a[1] *= inv; a[2] *= inv; a[3] *= inv;
    *(f32x4*)(ob + 4 * j) = a;
  }
}

extern "C" void kernel_launch(void* const* d_in, const int* in_sizes, int n_in,
                              void* d_out, int out_size, void* d_ws, size_t ws_size,
                              hipStream_t stream) {
  (void)in_sizes; (void)n_in; (void)out_size;
  const float* q = (const float*)d_in[0];
  const float* k = (const float*)d_in[1];
  const float* v = (const float*)d_in[2];
  const int* maskp = (const int*)d_in[3];
  float* out = (float*)d_out;

  const size_t elems = (size_t)16 * T_SEQ * DH;   // 4,194,304 per tensor
  unsigned short* Kb = (unsigned short*)d_ws;     // 8MB
  unsigned short* Vt = Kb + elems;                // 8MB
  float* Part = (float*)d_ws + elems;             // after 16MB: 576 slots * 16640 f32 = 38.3MB
  const int use_split = (ws_size >= WS_NEEDED) ? 1 : 0;

  prep_kv<<<dim3(320, 16), 256, 0, stream>>>(k, v, Kb, Vt);
  attn_fwd<<<dim3(640), 512, 0, stream>>>(q, Kb, Vt, out, Part, maskp, use_split);
  combine_kernel<<<dim3(192), 256, 0, stream>>>(Part, out, maskp, use_split);
}

// Round 9
// 156.054 us; speedup vs baseline: 1.5051x; 1.0276x over previous
//
#include <hip/hip_runtime.h>
#include <hip/hip_bf16.h>
#include <stdint.h>

#define T_SEQ 2048
#define DH    128
#define BKV   64
#define QSCALE 0.12751742796f   // (1/sqrt(128)) * log2(e): exp2-domain softmax
#define SLOT_F 16640             // partial slot: m[128], s[128], O[128][128] floats
#define WS_NEEDED 55115776ULL    // 16.8MB bf16 K/V^T + 38.3MB partials (576 slots)

typedef short  short8 __attribute__((ext_vector_type(8)));
typedef __bf16 bf16x8 __attribute__((ext_vector_type(8)));
typedef float  f32x4  __attribute__((ext_vector_type(4)));

__device__ __forceinline__ bf16x8 as_bf16x8(short8 x) { return __builtin_bit_cast(bf16x8, x); }

__device__ __forceinline__ uint32_t bf_bits(float x) {
  union { __hip_bfloat16 h; unsigned short u; } cv;
  cv.h = __float2bfloat16(x);
  return (uint32_t)cv.u;
}

// ---------------- merged pre-pass: K fp32->bf16, V[n][t][d] -> Vt[n][d][t'] bf16 ----------------
// Vt stores kv-PERMUTED columns: within each 32-kv block, position k holds source offset
// sigma(k) = 16*((k>>2)&1) + 4*((k>>3)&3) + (k&3). This aligns the PV mfma's B-fragment
// k-slots with the P values each lane already holds after QK^T (see attn_fwd), eliminating
// the 16 ds_bpermute redistribution. PV contracts over k with BOTH operands permuted by the
// same bijection -> result unchanged.
// grid (320, 16), 256 threads. x<256: K convert. x>=256: V 64x64 transpose tile.
__global__ void prep_kv(const float* __restrict__ k, const float* __restrict__ v,
                        unsigned short* __restrict__ kb, unsigned short* __restrict__ vt) {
  __shared__ float tile[64][65];
  const int n = blockIdx.y, x = blockIdx.x, tid = threadIdx.x;
  if (x < 256) {
    const int i = (n * 256 + x) * 256 + tid;     // float4 index into K
    const float4 f = ((const float4*)k)[i];
    union { unsigned short us[4]; uint2 u2; } o;
    o.us[0] = (unsigned short)bf_bits(f.x);
    o.us[1] = (unsigned short)bf_bits(f.y);
    o.us[2] = (unsigned short)bf_bits(f.z);
    o.us[3] = (unsigned short)bf_bits(f.w);
    ((uint2*)kb)[i] = o.u2;
  } else {
    const int x2 = x - 256;
    const int t0 = (x2 & 31) * 64, d0 = (x2 >> 5) * 64;
    const int tx = tid & 63, ty = tid >> 6;      // (64, 4)
    #pragma unroll
    for (int i = 0; i < 64; i += 4)
      tile[ty + i][tx] = v[((size_t)n * T_SEQ + t0 + ty + i) * DH + d0 + tx];
    __syncthreads();
    // kv permutation within each 32-block (tx = dest position, sig = source t-offset)
    const int sig = 32 * (tx >> 5) + 16 * ((tx >> 2) & 1) + 4 * ((tx >> 3) & 3) + (tx & 3);
    #pragma unroll
    for (int i = 0; i < 64; i += 4)
      vt[((size_t)n * DH + d0 + ty + i) * T_SEQ + t0 + tx] = (unsigned short)bf_bits(tile[sig][ty + i]);
  }
}

// ---------------- flash attention fwd (causal), bf16 MFMA, 8-wave blocks, uniform KV-chunks ----------------
// Block = one job (n, Q, chunk c): 128 q-rows (wave w owns rows Q*128+16w..+15), KV tiles
// kt in [8c, min(8c+8, 2Q+2)). 8 waves share one K/V LDS tile; double-buffered LDS (64KB),
// one barrier per tile. Defer-max (T13). P^T feeds PV DIRECTLY from registers: the kv
// dimension of V^T is pre-permuted (see prep_kv) so lane (q=m15, g) B-fragment slot
// k=8g+j maps to kv=16*(2ks+(j>>2))+4g+(j&3) -- exactly p[2ks+(j>>2)][j&3], zero shuffles.
// __launch_bounds__(512, 4): VGPR cap 128 (R6's (512,6) caused spill catastrophe).
// S^T = mfma(A=K_tile, B=Q): lane holds S for q = lane&15, kv = 16*ma + 4*(lane>>4) + reg.
// O^T = mfma(A=V^T_tile, B=P^T): lane holds O for q = lane&15, d = 16*dsub + 4*(lane>>4) + reg.
// Fragment layout (HW-verified, m97/m89): A/B lane l <-> [l&15][(l>>4)*8+j]; C/D col=l&15, row=(l>>4)*4+reg.
__global__ __launch_bounds__(512, 4) void attn_fwd(
    const float* __restrict__ Qf,
    const unsigned short* __restrict__ Kb,
    const unsigned short* __restrict__ Vt,
    float* __restrict__ Out,
    float* __restrict__ Part,
    const int* __restrict__ maskp,
    int use_split)
{
  __shared__ __align__(16) char smem[65536];  // K bufs @0,@16384; V^T bufs @32768,@49152

  const int tid  = threadIdx.x;
  const int lane = tid & 63;
  const int w    = tid >> 6;                  // 0..7
  const int m15  = lane & 15;
  const int g    = lane >> 4;

  // XCD L2 affinity: XCD = bid%8 serves n in {r, r+8} (2MB K+V bf16 < 4MB per-XCD L2).
  const int bid = blockIdx.x;
  const int n   = (bid & 7) + 8 * ((bid >> 3) & 1);
  const int job = bid >> 4;                    // 0..39
  const int masked = maskp[0];

  int Q, c, k0, k1, nc;
  if (masked && use_split) {
    // jobs enumerate (Q, chunk): tiles(Q) = 2Q+2, nc(Q) = ceil((2Q+2)/8) = (2Q+9)>>3; sum = 40.
    int base = 0; Q = 0;
    for (;;) { int ncq = (2 * Q + 9) >> 3; if (job < base + ncq) { c = job - base; break; } base += ncq; ++Q; }
    nc = (2 * Q + 9) >> 3;
    k0 = c * 8;
    k1 = min(k0 + 8, 2 * Q + 2);
  } else {
    if (job >= 16) return;                     // fallback / unmasked: one job per q-block
    Q = job; c = 0; nc = 1; k0 = 0;
    k1 = masked ? (2 * Q + 2) : (T_SEQ / BKV);
  }

  const int qrow = Q * 128 + 16 * w + m15;

  // Q B-fragments, fp32 -> bf16 in-kernel with scale*log2e folded:
  // lane needs Q[q-row][k = 32*kf + 8*g + j], j=0..7.
  bf16x8 qf[4];
  {
    const float* qg = Qf + ((size_t)n * T_SEQ + qrow) * DH;
    #pragma unroll
    for (int kf = 0; kf < 4; ++kf) {
      const float4 f0 = *(const float4*)(qg + 32 * kf + 8 * g);
      const float4 f1 = *(const float4*)(qg + 32 * kf + 8 * g + 4);
      union { unsigned short us[8]; short8 s8; } qa;
      qa.us[0] = (unsigned short)bf_bits(f0.x * QSCALE);
      qa.us[1] = (unsigned short)bf_bits(f0.y * QSCALE);
      qa.us[2] = (unsigned short)bf_bits(f0.z * QSCALE);
      qa.us[3] = (unsigned short)bf_bits(f0.w * QSCALE);
      qa.us[4] = (unsigned short)bf_bits(f1.x * QSCALE);
      qa.us[5] = (unsigned short)bf_bits(f1.y * QSCALE);
      qa.us[6] = (unsigned short)bf_bits(f1.z * QSCALE);
      qa.us[7] = (unsigned short)bf_bits(f1.w * QSCALE);
      qf[kf] = as_bf16x8(qa.s8);
    }
  }

  f32x4 acc[8] = {};
  float m_run = -3.0e38f;
  float ssum  = 0.f;
  const int swz = (m15 & 7) << 4;  // XOR swizzle for LDS reads (row&7 == m15&7 for K and V^T)

  short8 kreg[2], vreg[2];
  const short8* gK = (const short8*)(Kb + (size_t)n * T_SEQ * DH);   // [2048][16] short8
  const short8* gV = (const short8*)(Vt + (size_t)n * DH * T_SEQ);   // [128][256] short8

  auto loadRegs = [&](int kt) {
    const int t0 = kt * BKV;
    #pragma unroll
    for (int i = 0; i < 2; ++i) {                 // K: wave w stages rows 8w..8w+7, 16B chunk = m15
      int row = 8 * w + 4 * i + g;
      kreg[i] = gK[(size_t)(t0 + row) * 16 + m15];
    }
    #pragma unroll
    for (int i = 0; i < 2; ++i) {                 // V^T: wave w stages d 16w..16w+15, chunk = lane&7
      int d = 16 * w + 8 * i + (lane >> 3);
      vreg[i] = gV[(size_t)d * 256 + (t0 >> 3) + (lane & 7)];
    }
  };
  auto writeRegs = [&](int buf) {                 // swizzled ds_write_b128, double buffer
    #pragma unroll
    for (int i = 0; i < 2; ++i) {
      int row = 8 * w + 4 * i + g;
      int off = buf * 16384 + row * 256 + ((m15 * 16) ^ ((row & 7) << 4));
      *(short8*)(smem + off) = kreg[i];
    }
    #pragma unroll
    for (int i = 0; i < 2; ++i) {
      int d = 16 * w + 8 * i + (lane >> 3);
      int off = 32768 + buf * 16384 + d * 128 + (((lane & 7) * 16) ^ ((d & 7) << 4));
      *(short8*)(smem + off) = vreg[i];
    }
  };

  loadRegs(k0);
  writeRegs(k0 & 1);

  for (int kt = k0; kt < k1; ++kt) {
    __syncthreads();                              // tile kt visible; all reads of buf (kt+1)&1 done
    if (kt + 1 < k1) loadRegs(kt + 1);            // issue next-tile global loads early

    const char* kb = smem + (kt & 1) * 16384;
    const char* vb = smem + 32768 + (kt & 1) * 16384;

    // ---- S^T[64 kv][16 q] = K_tile * Q^T ----
    f32x4 s[4] = {};
    __builtin_amdgcn_s_setprio(1);
    #pragma unroll
    for (int kf = 0; kf < 4; ++kf) {
      #pragma unroll
      for (int ma = 0; ma < 4; ++ma) {
        short8 kfr = *(const short8*)(kb + (16 * ma + m15) * 256 + ((g * 16 + 64 * kf) ^ swz));
        s[ma] = __builtin_amdgcn_mfma_f32_16x16x32_bf16(as_bf16x8(kfr), qf[kf], s[ma], 0, 0, 0);
      }
    }
    __builtin_amdgcn_s_setprio(0);

    if (masked && kt >= 2 * Q) {                  // last-two tiles: causal mask
      #pragma unroll
      for (int ma = 0; ma < 4; ++ma)
        #pragma unroll
        for (int rr = 0; rr < 4; ++rr) {
          int kvg = kt * BKV + ma * 16 + g * 4 + rr;
          if (kvg > qrow) s[ma][rr] = -1.0e30f;
        }
    }

    // ---- online softmax (exp2 domain); row q = m15 lives on lanes {q, q+16, q+32, q+48} ----
    float mx = s[0][0];
    #pragma unroll
    for (int ma = 0; ma < 4; ++ma)
      #pragma unroll
      for (int rr = 0; rr < 4; ++rr) mx = fmaxf(mx, s[ma][rr]);
    mx = fmaxf(mx, __shfl_xor(mx, 16));
    mx = fmaxf(mx, __shfl_xor(mx, 32));

    // defer-max (T13): only rescale when some row's max grew by >8; P bounded by 2^8.
    if (!__all(mx <= m_run + 8.0f)) {
      float mnew = fmaxf(m_run, mx);
      float corr = exp2f(m_run - mnew);
      ssum *= corr;
      #pragma unroll
      for (int i = 0; i < 8; ++i) {
        acc[i][0] *= corr; acc[i][1] *= corr; acc[i][2] *= corr; acc[i][3] *= corr;
      }
      m_run = mnew;
    }

    float p[4][4];
    float lsum = 0.f;
    #pragma unroll
    for (int ma = 0; ma < 4; ++ma)
      #pragma unroll
      for (int rr = 0; rr < 4; ++rr) { p[ma][rr] = exp2f(s[ma][rr] - m_run); lsum += p[ma][rr]; }
    lsum += __shfl_xor(lsum, 16);
    lsum += __shfl_xor(lsum, 32);
    ssum += lsum;

    // ---- pack P to bf16 pairs: u[ma][wd] = (p[ma][2wd], p[ma][2wd+1]) ----
    uint32_t u[4][2];
    #pragma unroll
    for (int ma = 0; ma < 4; ++ma) {
      u[ma][0] = bf_bits(p[ma][0]) | (bf_bits(p[ma][1]) << 16);
      u[ma][1] = bf_bits(p[ma][2]) | (bf_bits(p[ma][3]) << 16);
    }

    // ---- B-fragments directly from registers (kv-permuted V layout, see prep_kv) ----
    // slot k=8g+j of pfr[ks] <-> kv = 16*(2ks+(j>>2)) + 4g + (j&3) = p[2ks+(j>>2)][j&3].
    bf16x8 pfr[2];
    #pragma unroll
    for (int ks = 0; ks < 2; ++ks) {
      union { uint32_t q[4]; short8 s8; } pu;
      pu.q[0] = u[2 * ks + 0][0];
      pu.q[1] = u[2 * ks + 0][1];
      pu.q[2] = u[2 * ks + 1][0];
      pu.q[3] = u[2 * ks + 1][1];
      pfr[ks] = as_bf16x8(pu.s8);
    }

    // ---- O^T[128 d][16 q] += V^T_tile * P^T ----
    __builtin_amdgcn_s_setprio(1);
    #pragma unroll
    for (int dsub = 0; dsub < 8; ++dsub) {
      #pragma unroll
      for (int ks = 0; ks < 2; ++ks) {
        short8 vfr = *(const short8*)(vb + (16 * dsub + m15) * 128 + ((g * 16 + 64 * ks) ^ swz));
        acc[dsub] = __builtin_amdgcn_mfma_f32_16x16x32_bf16(as_bf16x8(vfr), pfr[ks], acc[dsub], 0, 0, 0);
      }
    }
    __builtin_amdgcn_s_setprio(0);

    if (kt + 1 < k1) writeRegs((kt + 1) & 1);     // stage tile kt+1 into the other buffer
  }

  if (nc == 1) {
    // single chunk: final result, normalize and write Out
    const float inv = 1.0f / ssum;
    float* ob = Out + ((size_t)n * T_SEQ + qrow) * DH;
    #pragma unroll
    for (int dsub = 0; dsub < 8; ++dsub) {
      f32x4 o;
      o[0] = acc[dsub][0] * inv; o[1] = acc[dsub][1] * inv;
      o[2] = acc[dsub][2] * inv; o[3] = acc[dsub][3] * inv;
      *(f32x4*)(ob + dsub * 16 + g * 4) = o;
    }
  } else {
    // partial slot (tight pack over Q>=4): slot = n*36 + b8 + c, b8 = sum_{4<=Q'<Q} nc(Q')
    int b8 = 0;
    for (int qq = 4; qq < Q; ++qq) b8 += (2 * qq + 9) >> 3;
    float* slot = Part + ((size_t)n * 36 + b8 + c) * SLOT_F;
    const int qr = 16 * w + m15;
    if (g == 0) { slot[qr] = m_run; slot[128 + qr] = ssum; }
    float* so = slot + 256 + (size_t)qr * 128;
    #pragma unroll
    for (int dsub = 0; dsub < 8; ++dsub)
      *(f32x4*)(so + dsub * 16 + 4 * g) = acc[dsub];
  }
}

// ---------------- combine partial chunks (masked split path only) ----------------
__global__ void combine_kernel(const float* __restrict__ Part, float* __restrict__ Out,
                               const int* __restrict__ maskp, int use_split) {
  if (!maskp[0] || !use_split) return;
  const int cb = blockIdx.x;                      // 0..191
  const int n  = cb & 15;
  const int Q  = (cb >> 4) + 4;
  const int nc = (2 * Q + 9) >> 3;                // 2..4
  int b8 = 0;
  for (int qq = 4; qq < Q; ++qq) b8 += (2 * qq + 9) >> 3;
  const float* slot0 = Part + ((size_t)n * 36 + b8) * SLOT_F;

  const int tid = threadIdx.x;
  const int q   = tid >> 1;                       // 0..127
  const int d0  = (tid & 1) * 64;

  float m[4], s[4], wgt[4];
  float M = -3.0e38f;
  for (int i = 0; i < nc; ++i) {
    m[i] = slot0[(size_t)i * SLOT_F + q];
    s[i] = slot0[(size_t)i * SLOT_F + 128 + q];
    M = fmaxf(M, m[i]);
  }
  float denom = 0.f;
  for (int i = 0; i < nc; ++i) { wgt[i] = exp2f(m[i] - M); denom += s[i] * wgt[i]; }
  const float inv = 1.0f / denom;

  float* ob = Out + ((size_t)n * T_SEQ + Q * 128 + q) * DH + d0;
  #pragma unroll
  for (int j = 0; j < 16; ++j) {
    f32x4 a = {};
    for (int i = 0; i < nc; ++i) {
      const f32x4 v = *(const f32x4*)(slot0 + (size_t)i * SLOT_F + 256 + (size_t)q * 128 + d0 + 4 * j);
      a[0] += v[0] * wgt[i]; a[1] += v[1] * wgt[i]; a[2] += v[2] * wgt[i]; a[3] += v[3] * wgt[i];
    }
    a[0] *= inv; a[1] *= inv; a[2] *= inv; a[3] *= inv;
    *(f32x4*)(ob + 4 * j) = a;
  }
}

extern "C" void kernel_launch(void* const* d_in, const int* in_sizes, int n_in,
                              void* d_out, int out_size, void* d_ws, size_t ws_size,
                              hipStream_t stream) {
  (void)in_sizes; (void)n_in; (void)out_size;
  const float* q = (const float*)d_in[0];
  const float* k = (const float*)d_in[1];
  const float* v = (const float*)d_in[2];
  const int* maskp = (const int*)d_in[3];
  float* out = (float*)d_out;

  const size_t elems = (size_t)16 * T_SEQ * DH;   // 4,194,304 per tensor
  unsigned short* Kb = (unsigned short*)d_ws;     // 8MB
  unsigned short* Vt = Kb + elems;                // 8MB
  float* Part = (float*)d_ws + elems;             // after 16MB: 576 slots * 16640 f32 = 38.3MB
  const int use_split = (ws_size >= WS_NEEDED) ? 1 : 0;

  prep_kv<<<dim3(320, 16), 256, 0, stream>>>(k, v, Kb, Vt);
  attn_fwd<<<dim3(640), 512, 0, stream>>>(q, Kb, Vt, out, Part, maskp, use_split);
  combine_kernel<<<dim3(192), 256, 0, stream>>>(Part, out, maskp, use_split);
}